// Round 1
// baseline (1693.235 us; speedup 1.0000x reference)
//
#include <hip/hip_runtime.h>
#include <math.h>

#define BB 8
#define VV 2
#define HH 1024
#define WW 1024
#define NPTS 131072
#define IMG (HH*WW)
#define FUSED (VV*BB*IMG)   // 16777216

// ---- workspace layout (bytes). Small stuff first so a fallback path works
// even if ws is small; winner array (64 MiB) last.
#define OFF_PD   0u                              // double[16*12]  = 1536 B
#define OFF_E2   1536u                           // double[16*4]   = 512 B
#define OFF_HAS  2048u                           // int[8]
#define OFF_VAL  2304u                           // float[2*NPTS]  = 1 MiB
#define OFF_PIX  (2304u + 4u*2u*NPTS)            // int[2*NPTS]    = 1 MiB
#define OFF_WIN  (OFF_PIX + 4u*2u*NPTS)          // int[FUSED]     = 64 MiB
#define WS_NEED  ((size_t)OFF_WIN + 4ull*(size_t)FUSED)

__device__ __forceinline__ int clampi(int v, int lo, int hi) {
    return v < lo ? lo : (v > hi ? hi : v);
}

// K1: per-(b,v) P = (intr*rowscale) @ inv(E)[:3,:], e2 = inv(E)[2,:]; init reduction cells.
__global__ void prep_kernel(const float* __restrict__ intr,
                            const float* __restrict__ extr,
                            float* __restrict__ out, char* __restrict__ ws) {
    double* Pd  = (double*)(ws + OFF_PD);
    double* e2d = (double*)(ws + OFF_E2);
    int*    hasb = (int*)(ws + OFF_HAS);
    int t = threadIdx.x;
    if (t < BB) hasb[t] = 0;
    if (t < BB * VV) {
        float* near_ = out + FUSED;
        float* far_  = out + FUSED + BB * VV;
        near_[t] = INFINITY;   // bits 0x7F800000, positive -> signed-int atomicMin ok
        far_[t]  = 0.0f;       // bits 0 -> any positive z beats it under atomicMax
        // Gauss-Jordan inverse of 4x4 extrinsic, f64, partial pivoting
        const float* E = extr + t * 16;
        double a[4][8];
        for (int i = 0; i < 4; i++)
            for (int j = 0; j < 4; j++) {
                a[i][j]     = (double)E[i * 4 + j];
                a[i][4 + j] = (i == j) ? 1.0 : 0.0;
            }
        for (int c = 0; c < 4; c++) {
            int piv = c; double best = fabs(a[c][c]);
            for (int r = c + 1; r < 4; r++) {
                double v = fabs(a[r][c]);
                if (v > best) { best = v; piv = r; }
            }
            if (piv != c)
                for (int j = 0; j < 8; j++) {
                    double tmp = a[c][j]; a[c][j] = a[piv][j]; a[piv][j] = tmp;
                }
            double inv = 1.0 / a[c][c];
            for (int j = 0; j < 8; j++) a[c][j] *= inv;
            for (int r = 0; r < 4; r++) {
                if (r == c) continue;
                double f = a[r][c];
                for (int j = 0; j < 8; j++) a[r][j] -= f * a[c][j];
            }
        }
        // P[i][k] = sum_j intr[i][j]*rowscale[i] * Einv[j][k]
        const float* K = intr + t * 9;
        double rs[3] = {(double)WW, (double)HH, 1.0};
        for (int i = 0; i < 3; i++)
            for (int k = 0; k < 4; k++) {
                double s = 0.0;
                for (int j = 0; j < 3; j++) s += (double)K[i * 3 + j] * rs[i] * a[j][4 + k];
                Pd[t * 12 + i * 4 + k] = s;
            }
        for (int k = 0; k < 4; k++) e2d[t * 4 + k] = a[2][4 + k];
    }
}

// K2: bulk copy disps -> fused output (memory-bound, float4)
__global__ void copy_kernel(const float4* __restrict__ src, float4* __restrict__ dst) {
    int i = blockIdx.x * blockDim.x + threadIdx.x;
    dst[i] = src[i];
}

// K2b: clear winner cells for every touched pixel (robust to ws poison value)
__global__ void clear_kernel(const float* __restrict__ mk0, const float* __restrict__ mk1,
                             const int* __restrict__ mbids, char* __restrict__ ws) {
    int id = blockIdx.x * blockDim.x + threadIdx.x;
    if (id >= 2 * NPTS) return;
    int n = id >> 1, v = id & 1;
    const float* mk = v ? mk1 : mk0;
    int xi = clampi((int)mk[2 * n], 0, WW - 1);
    int yi = clampi((int)mk[2 * n + 1], 0, HH - 1);
    int bid = mbids[n];
    int* winner = (int*)(ws + OFF_WIN);
    winner[(v * BB + bid) * IMG + yi * WW + xi] = -1;
}

// K3: per-point 4x4 AtA Jacobi eigensolve, z/valid, near-far atomics, scatter vote
template <bool DIRECT>
__global__ void solve_kernel(const float* __restrict__ mk0, const float* __restrict__ mk1,
                             const int* __restrict__ mbids, const float* __restrict__ disps,
                             float* __restrict__ out, char* __restrict__ ws) {
    int n = blockIdx.x * blockDim.x + threadIdx.x;
    if (n >= NPTS) return;
    const double* Pd  = (const double*)(ws + OFF_PD);
    const double* e2d = (const double*)(ws + OFF_E2);
    int*   hasb   = (int*)(ws + OFF_HAS);
    float* valarr = (float*)(ws + OFF_VAL);
    int*   pixarr = (int*)(ws + OFF_PIX);
    int*   winner = (int*)(ws + OFF_WIN);

    int bid = mbids[n];
    float xf[2] = {mk0[2 * n], mk1[2 * n]};
    float yf[2] = {mk0[2 * n + 1], mk1[2 * n + 1]};

    // M = A^T A  (mconf is a uniform positive scale of A -> no effect on eigvecs)
    double M[4][4];
#pragma unroll
    for (int i = 0; i < 4; i++)
#pragma unroll
        for (int j = 0; j < 4; j++) M[i][j] = 0.0;
#pragma unroll
    for (int v = 0; v < 2; v++) {
        const double* P = Pd + (bid * VV + v) * 12;
        double xx = (double)xf[v], yy = (double)yf[v];
        double r0[4], r1[4];
#pragma unroll
        for (int j = 0; j < 4; j++) {
            r0[j] = xx * P[8 + j] - P[j];
            r1[j] = yy * P[8 + j] - P[4 + j];
        }
#pragma unroll
        for (int i = 0; i < 4; i++)
#pragma unroll
            for (int j = 0; j < 4; j++) M[i][j] += r0[i] * r0[j] + r1[i] * r1[j];
    }

    // cyclic Jacobi, f64, eigvec accumulation in Vm
    double Vm[4][4] = {{1, 0, 0, 0}, {0, 1, 0, 0}, {0, 0, 1, 0}, {0, 0, 0, 1}};
    for (int sweep = 0; sweep < 12; ++sweep) {
        double off = fabs(M[0][1]) + fabs(M[0][2]) + fabs(M[0][3]) +
                     fabs(M[1][2]) + fabs(M[1][3]) + fabs(M[2][3]);
        double dia = fabs(M[0][0]) + fabs(M[1][1]) + fabs(M[2][2]) + fabs(M[3][3]);
        if (off <= 1e-14 * dia) break;
#pragma unroll
        for (int p = 0; p < 3; p++) {
#pragma unroll
            for (int q = p + 1; q < 4; q++) {
                double apq = M[p][q];
                if (fabs(apq) < 1e-300) continue;
                double tau = (M[q][q] - M[p][p]) / (2.0 * apq);
                double rt  = sqrt(1.0 + tau * tau);
                double t_  = (tau >= 0.0) ? 1.0 / (tau + rt) : 1.0 / (tau - rt);
                double c = 1.0 / sqrt(1.0 + t_ * t_);
                double s = t_ * c;
#pragma unroll
                for (int k = 0; k < 4; k++) {        // M := M*J (columns)
                    double mp = M[k][p], mq = M[k][q];
                    M[k][p] = c * mp - s * mq;
                    M[k][q] = s * mp + c * mq;
                }
#pragma unroll
                for (int k = 0; k < 4; k++) {        // M := J^T*M (rows)
                    double mp = M[p][k], mq = M[q][k];
                    M[p][k] = c * mp - s * mq;
                    M[q][k] = s * mp + c * mq;
                }
#pragma unroll
                for (int k = 0; k < 4; k++) {        // Vm := Vm*J
                    double vp = Vm[k][p], vq = Vm[k][q];
                    Vm[k][p] = c * vp - s * vq;
                    Vm[k][q] = s * vp + c * vq;
                }
            }
        }
    }
    int jmin = 0; double dmin = M[0][0];
#pragma unroll
    for (int j = 1; j < 4; j++)
        if (M[j][j] < dmin) { dmin = M[j][j]; jmin = j; }

    double h3 = Vm[3][jmin];
    double iw = 1.0 / h3;
    double pwx = Vm[0][jmin] * iw, pwy = Vm[1][jmin] * iw, pwz = Vm[2][jmin] * iw;

    double z[2];
#pragma unroll
    for (int v = 0; v < 2; v++) {
        const double* e = e2d + (bid * VV + v) * 4;
        z[v] = e[0] * pwx + e[1] * pwy + e[2] * pwz + e[3];
    }
    bool valid = (z[0] > 0.0) && (z[0] < 500.0) && (z[1] > 0.0) && (z[1] < 500.0);

    if (valid) {
        float* near_ = out + FUSED;
        float* far_  = out + FUSED + BB * VV;
#pragma unroll
        for (int v = 0; v < 2; v++) {
            int fb = __float_as_int((float)z[v]);
            atomicMin((int*)(near_ + bid * VV + v), fb);
            atomicMax((int*)(far_  + bid * VV + v), fb);
        }
        atomicOr(hasb + bid, 1);
    }

#pragma unroll
    for (int v = 0; v < 2; v++) {
        int xi = clampi((int)xf[v], 0, WW - 1);
        int yi = clampi((int)yf[v], 0, HH - 1);
        int pix = (v * BB + bid) * IMG + yi * WW + xi;
        float cost = disps[pix];
        float val = valid ? (float)(0.5 * (1.0 / z[v]) + 0.5 * (double)cost) : cost;
        if (DIRECT) {
            out[pix] = val;   // fallback: nondeterministic duplicate order
        } else {
            valarr[2 * n + v] = val;
            pixarr[2 * n + v] = pix;
            atomicMax(winner + pix, n);   // last-update-wins == max n
        }
    }
}

// K4: winner writes its val (deterministic duplicate resolution)
__global__ void resolve_kernel(float* __restrict__ out, const char* __restrict__ ws) {
    int id = blockIdx.x * blockDim.x + threadIdx.x;
    if (id >= 2 * NPTS) return;
    const float* valarr = (const float*)(ws + OFF_VAL);
    const int*   pixarr = (const int*)(ws + OFF_PIX);
    const int*   winner = (const int*)(ws + OFF_WIN);
    int pix = pixarr[id];
    if (winner[pix] == (id >> 1)) out[pix] = valarr[id];
}

// K5: apply flag gating to near/far, write flag
__global__ void finalize_kernel(float* __restrict__ out, const char* __restrict__ ws) {
    int t = threadIdx.x;
    if (t >= BB * VV) return;
    const int* hasb = (const int*)(ws + OFF_HAS);
    int has = hasb[t / VV];
    float* near_ = out + FUSED;
    float* far_  = out + FUSED + BB * VV;
    float* flag_ = out + FUSED + 2 * BB * VV;
    near_[t] = has ? near_[t] : 0.0f;
    far_[t]  = has ? far_[t]  : 500.0f;
    flag_[t] = has ? 1.0f : 0.0f;
}

extern "C" void kernel_launch(void* const* d_in, const int* in_sizes, int n_in,
                              void* d_out, int out_size, void* d_ws, size_t ws_size,
                              hipStream_t stream) {
    const float* mk0   = (const float*)d_in[0];
    const float* mk1   = (const float*)d_in[1];
    // d_in[2] = mconf: uniform positive scale of A, no effect on the null vector -> unused
    const int*   mbids = (const int*)d_in[3];
    const float* intr  = (const float*)d_in[4];
    const float* extr  = (const float*)d_in[5];
    const float* disps = (const float*)d_in[6];
    float* out = (float*)d_out;
    char*  ws  = (char*)d_ws;

    bool dedup = (ws_size >= WS_NEED);

    prep_kernel<<<1, 64, 0, stream>>>(intr, extr, out, ws);
    copy_kernel<<<FUSED / 4 / 256, 256, 0, stream>>>((const float4*)disps, (float4*)out);
    if (dedup) {
        clear_kernel<<<(2 * NPTS + 255) / 256, 256, 0, stream>>>(mk0, mk1, mbids, ws);
        solve_kernel<false><<<(NPTS + 255) / 256, 256, 0, stream>>>(mk0, mk1, mbids, disps, out, ws);
        resolve_kernel<<<(2 * NPTS + 255) / 256, 256, 0, stream>>>(out, ws);
    } else {
        solve_kernel<true><<<(NPTS + 255) / 256, 256, 0, stream>>>(mk0, mk1, mbids, disps, out, ws);
    }
    finalize_kernel<<<1, 64, 0, stream>>>(out, ws);
}

// Round 2
// 1686.123 us; speedup vs baseline: 1.0042x; 1.0042x over previous
//
#include <hip/hip_runtime.h>
#include <math.h>

#define BB 8
#define VV 2
#define HH 1024
#define WW 1024
#define NPTS 131072
#define IMG (HH*WW)
#define FUSED (VV*BB*IMG)   // 16777216

// ---- workspace layout (bytes). Small stuff first; winner array (64 MiB) last.
#define OFF_PD   0u                              // double[16*12]  = 1536 B
#define OFF_E2   1536u                           // double[16*4]   = 512 B
#define OFF_HAS  2048u                           // int[8]
#define OFF_VAL  2304u                           // float[2*NPTS]  = 1 MiB
#define OFF_PIX  (2304u + 4u*2u*NPTS)            // int[2*NPTS]    = 1 MiB
#define OFF_WIN  (OFF_PIX + 4u*2u*NPTS)          // int[FUSED]     = 64 MiB
#define WS_NEED  ((size_t)OFF_WIN + 4ull*(size_t)FUSED)

__device__ __forceinline__ int clampi(int v, int lo, int hi) {
    return v < lo ? lo : (v > hi ? hi : v);
}

// K1: per-(b,v) P = (intr*rowscale) @ inv(E)[:3,:], e2 = inv(E)[2,:]; init reduction cells.
__global__ __launch_bounds__(64) void prep_kernel(const float* __restrict__ intr,
                            const float* __restrict__ extr,
                            float* __restrict__ out, char* __restrict__ ws) {
    double* Pd  = (double*)(ws + OFF_PD);
    double* e2d = (double*)(ws + OFF_E2);
    int*    hasb = (int*)(ws + OFF_HAS);
    int t = threadIdx.x;
    if (t < BB) hasb[t] = 0;
    if (t < BB * VV) {
        float* near_ = out + FUSED;
        float* far_  = out + FUSED + BB * VV;
        near_[t] = INFINITY;   // positive -> signed-int atomicMin ok
        far_[t]  = 0.0f;       // any positive z beats it under signed atomicMax
        // Gauss-Jordan inverse of 4x4 extrinsic, f64, partial pivoting
        const float* E = extr + t * 16;
        double a[4][8];
        for (int i = 0; i < 4; i++)
            for (int j = 0; j < 4; j++) {
                a[i][j]     = (double)E[i * 4 + j];
                a[i][4 + j] = (i == j) ? 1.0 : 0.0;
            }
        for (int c = 0; c < 4; c++) {
            int piv = c; double best = fabs(a[c][c]);
            for (int r = c + 1; r < 4; r++) {
                double v = fabs(a[r][c]);
                if (v > best) { best = v; piv = r; }
            }
            if (piv != c)
                for (int j = 0; j < 8; j++) {
                    double tmp = a[c][j]; a[c][j] = a[piv][j]; a[piv][j] = tmp;
                }
            double inv = 1.0 / a[c][c];
            for (int j = 0; j < 8; j++) a[c][j] *= inv;
            for (int r = 0; r < 4; r++) {
                if (r == c) continue;
                double f = a[r][c];
                for (int j = 0; j < 8; j++) a[r][j] -= f * a[c][j];
            }
        }
        const float* K = intr + t * 9;
        double rs[3] = {(double)WW, (double)HH, 1.0};
        for (int i = 0; i < 3; i++)
            for (int k = 0; k < 4; k++) {
                double s = 0.0;
                for (int j = 0; j < 3; j++) s += (double)K[i * 3 + j] * rs[i] * a[j][4 + k];
                Pd[t * 12 + i * 4 + k] = s;
            }
        for (int k = 0; k < 4; k++) e2d[t * 4 + k] = a[2][4 + k];
    }
}

// K2: bulk copy disps -> fused output (memory-bound, float4)
__global__ __launch_bounds__(256) void copy_kernel(const float4* __restrict__ src,
                                                   float4* __restrict__ dst) {
    int i = blockIdx.x * blockDim.x + threadIdx.x;
    dst[i] = src[i];
}

// K2b: clear winner cells for every touched pixel (robust to ws poison value)
__global__ __launch_bounds__(256) void clear_kernel(const float* __restrict__ mk0,
                             const float* __restrict__ mk1,
                             const int* __restrict__ mbids, char* __restrict__ ws) {
    int id = blockIdx.x * blockDim.x + threadIdx.x;
    if (id >= 2 * NPTS) return;
    int n = id >> 1, v = id & 1;
    const float* mk = v ? mk1 : mk0;
    int xi = clampi((int)mk[2 * n], 0, WW - 1);
    int yi = clampi((int)mk[2 * n + 1], 0, HH - 1);
    int bid = mbids[n];
    int* winner = (int*)(ws + OFF_WIN);
    winner[(v * BB + bid) * IMG + yi * WW + xi] = -1;
}

// K3: per-point 4x4 AtA Jacobi eigensolve, z/valid, near-far atomics, scatter vote
template <bool DIRECT>
__global__ __launch_bounds__(256) void solve_kernel(const float* __restrict__ mk0,
                             const float* __restrict__ mk1,
                             const int* __restrict__ mbids, const float* __restrict__ disps,
                             float* __restrict__ out, char* __restrict__ ws) {
    int n = blockIdx.x * blockDim.x + threadIdx.x;
    if (n >= NPTS) return;
    const double* Pd  = (const double*)(ws + OFF_PD);
    const double* e2d = (const double*)(ws + OFF_E2);
    int*   hasb   = (int*)(ws + OFF_HAS);
    float* valarr = (float*)(ws + OFF_VAL);
    int*   pixarr = (int*)(ws + OFF_PIX);
    int*   winner = (int*)(ws + OFF_WIN);

    int bid = mbids[n];
    float xf[2] = {mk0[2 * n], mk1[2 * n]};
    float yf[2] = {mk0[2 * n + 1], mk1[2 * n + 1]};

    // M = A^T A  (mconf is a uniform positive scale of A -> no effect on eigvecs)
    double M[4][4];
#pragma unroll
    for (int i = 0; i < 4; i++)
#pragma unroll
        for (int j = 0; j < 4; j++) M[i][j] = 0.0;
#pragma unroll
    for (int v = 0; v < 2; v++) {
        const double* P = Pd + (bid * VV + v) * 12;
        double xx = (double)xf[v], yy = (double)yf[v];
        double r0[4], r1[4];
#pragma unroll
        for (int j = 0; j < 4; j++) {
            r0[j] = xx * P[8 + j] - P[j];
            r1[j] = yy * P[8 + j] - P[4 + j];
        }
#pragma unroll
        for (int i = 0; i < 4; i++)
#pragma unroll
            for (int j = 0; j < 4; j++) M[i][j] += r0[i] * r0[j] + r1[i] * r1[j];
    }

    // cyclic Jacobi, f64, eigvec accumulation in Vm
    double Vm[4][4] = {{1, 0, 0, 0}, {0, 1, 0, 0}, {0, 0, 1, 0}, {0, 0, 0, 1}};
    for (int sweep = 0; sweep < 8; ++sweep) {
        double off = fabs(M[0][1]) + fabs(M[0][2]) + fabs(M[0][3]) +
                     fabs(M[1][2]) + fabs(M[1][3]) + fabs(M[2][3]);
        double dia = fabs(M[0][0]) + fabs(M[1][1]) + fabs(M[2][2]) + fabs(M[3][3]);
        if (off <= 1e-14 * dia) break;
#pragma unroll
        for (int p = 0; p < 3; p++) {
#pragma unroll
            for (int q = p + 1; q < 4; q++) {
                double apq = M[p][q];
                if (fabs(apq) < 1e-300) continue;
                double tau = (M[q][q] - M[p][p]) / (2.0 * apq);
                double rt  = sqrt(1.0 + tau * tau);
                double t_  = (tau >= 0.0) ? 1.0 / (tau + rt) : 1.0 / (tau - rt);
                double c = 1.0 / sqrt(1.0 + t_ * t_);
                double s = t_ * c;
#pragma unroll
                for (int k = 0; k < 4; k++) {        // M := M*J (columns)
                    double mp = M[k][p], mq = M[k][q];
                    M[k][p] = c * mp - s * mq;
                    M[k][q] = s * mp + c * mq;
                }
#pragma unroll
                for (int k = 0; k < 4; k++) {        // M := J^T*M (rows)
                    double mp = M[p][k], mq = M[q][k];
                    M[p][k] = c * mp - s * mq;
                    M[q][k] = s * mp + c * mq;
                }
#pragma unroll
                for (int k = 0; k < 4; k++) {        // Vm := Vm*J
                    double vp = Vm[k][p], vq = Vm[k][q];
                    Vm[k][p] = c * vp - s * vq;
                    Vm[k][q] = s * vp + c * vq;
                }
            }
        }
    }
    int jmin = 0; double dmin = M[0][0];
#pragma unroll
    for (int j = 1; j < 4; j++)
        if (M[j][j] < dmin) { dmin = M[j][j]; jmin = j; }

    double h3 = Vm[3][jmin];
    double iw = 1.0 / h3;
    double pwx = Vm[0][jmin] * iw, pwy = Vm[1][jmin] * iw, pwz = Vm[2][jmin] * iw;

    double z[2];
#pragma unroll
    for (int v = 0; v < 2; v++) {
        const double* e = e2d + (bid * VV + v) * 4;
        z[v] = e[0] * pwx + e[1] * pwy + e[2] * pwz + e[3];
    }
    bool valid = (z[0] > 0.0) && (z[0] < 500.0) && (z[1] > 0.0) && (z[1] < 500.0);

    if (valid) {
        float* near_ = out + FUSED;
        float* far_  = out + FUSED + BB * VV;
#pragma unroll
        for (int v = 0; v < 2; v++) {
            int fb = __float_as_int((float)z[v]);
            atomicMin((int*)(near_ + bid * VV + v), fb);
            atomicMax((int*)(far_  + bid * VV + v), fb);
        }
        atomicOr(hasb + bid, 1);
    }

#pragma unroll
    for (int v = 0; v < 2; v++) {
        int xi = clampi((int)xf[v], 0, WW - 1);
        int yi = clampi((int)yf[v], 0, HH - 1);
        int pix = (v * BB + bid) * IMG + yi * WW + xi;
        float cost = disps[pix];
        float val = valid ? (float)(0.5 * (1.0 / z[v]) + 0.5 * (double)cost) : cost;
        if (DIRECT) {
            out[pix] = val;   // fallback: nondeterministic duplicate order
        } else {
            valarr[2 * n + v] = val;
            pixarr[2 * n + v] = pix;
            atomicMax(winner + pix, n);   // last-update-wins == max n
        }
    }
}

// K4: winner writes its val (deterministic duplicate resolution)
__global__ __launch_bounds__(256) void resolve_kernel(float* __restrict__ out,
                                                      const char* __restrict__ ws) {
    int id = blockIdx.x * blockDim.x + threadIdx.x;
    if (id >= 2 * NPTS) return;
    const float* valarr = (const float*)(ws + OFF_VAL);
    const int*   pixarr = (const int*)(ws + OFF_PIX);
    const int*   winner = (const int*)(ws + OFF_WIN);
    int pix = pixarr[id];
    if (winner[pix] == (id >> 1)) out[pix] = valarr[id];
}

// K5: apply flag gating to near/far, write flag
__global__ __launch_bounds__(64) void finalize_kernel(float* __restrict__ out,
                                                      const char* __restrict__ ws) {
    int t = threadIdx.x;
    if (t >= BB * VV) return;
    const int* hasb = (const int*)(ws + OFF_HAS);
    int has = hasb[t / VV];
    float* near_ = out + FUSED;
    float* far_  = out + FUSED + BB * VV;
    float* flag_ = out + FUSED + 2 * BB * VV;
    near_[t] = has ? near_[t] : 0.0f;
    far_[t]  = has ? far_[t]  : 500.0f;
    flag_[t] = has ? 1.0f : 0.0f;
}

extern "C" void kernel_launch(void* const* d_in, const int* in_sizes, int n_in,
                              void* d_out, int out_size, void* d_ws, size_t ws_size,
                              hipStream_t stream) {
    const float* mk0   = (const float*)d_in[0];
    const float* mk1   = (const float*)d_in[1];
    // d_in[2] = mconf: uniform positive scale of A, no effect on null vector -> unused
    const int*   mbids = (const int*)d_in[3];
    const float* intr  = (const float*)d_in[4];
    const float* extr  = (const float*)d_in[5];
    const float* disps = (const float*)d_in[6];
    float* out = (float*)d_out;
    char*  ws  = (char*)d_ws;

    bool dedup = (ws_size >= WS_NEED);

    prep_kernel<<<1, 64, 0, stream>>>(intr, extr, out, ws);
    copy_kernel<<<FUSED / 4 / 256, 256, 0, stream>>>((const float4*)disps, (float4*)out);
    if (dedup) {
        clear_kernel<<<(2 * NPTS + 255) / 256, 256, 0, stream>>>(mk0, mk1, mbids, ws);
        solve_kernel<false><<<(NPTS + 255) / 256, 256, 0, stream>>>(mk0, mk1, mbids, disps, out, ws);
        resolve_kernel<<<(2 * NPTS + 255) / 256, 256, 0, stream>>>(out, ws);
    } else {
        solve_kernel<true><<<(NPTS + 255) / 256, 256, 0, stream>>>(mk0, mk1, mbids, disps, out, ws);
    }
    finalize_kernel<<<1, 64, 0, stream>>>(out, ws);
}

// Round 3
// 225.896 us; speedup vs baseline: 7.4956x; 7.4641x over previous
//
#include <hip/hip_runtime.h>
#include <math.h>

#define BB 8
#define VV 2
#define HH 1024
#define WW 1024
#define NPTS 131072
#define IMG (HH*WW)
#define FUSED (VV*BB*IMG)   // 16777216

// ---- workspace layout (bytes). Small stuff first; winner array (64 MiB) last.
#define OFF_PD   0u                              // double[16*12]  = 1536 B
#define OFF_E2   1536u                           // double[16*4]   = 512 B
#define OFF_HAS  2048u                           // int[8]
#define OFF_VAL  2304u                           // float[2*NPTS]  = 1 MiB
#define OFF_PIX  (2304u + 4u*2u*NPTS)            // int[2*NPTS]    = 1 MiB
#define OFF_WIN  (OFF_PIX + 4u*2u*NPTS)          // int[FUSED]     = 64 MiB
#define WS_NEED  ((size_t)OFF_WIN + 4ull*(size_t)FUSED)

__device__ __forceinline__ int clampi(int v, int lo, int hi) {
    return v < lo ? lo : (v > hi ? hi : v);
}

// K1: per-(b,v) P = (intr*rowscale) @ inv(E)[:3,:], e2 = inv(E)[2,:]; init reduction cells.
__global__ __launch_bounds__(64) void prep_kernel(const float* __restrict__ intr,
                            const float* __restrict__ extr,
                            float* __restrict__ out, char* __restrict__ ws) {
    double* Pd  = (double*)(ws + OFF_PD);
    double* e2d = (double*)(ws + OFF_E2);
    int*    hasb = (int*)(ws + OFF_HAS);
    int t = threadIdx.x;
    if (t < BB) hasb[t] = 0;
    if (t < BB * VV) {
        float* near_ = out + FUSED;
        float* far_  = out + FUSED + BB * VV;
        near_[t] = INFINITY;   // positive -> signed-int atomicMin ok
        far_[t]  = 0.0f;       // any positive z beats it under signed atomicMax
        // Gauss-Jordan inverse of 4x4 extrinsic, f64, partial pivoting
        const float* E = extr + t * 16;
        double a[4][8];
        for (int i = 0; i < 4; i++)
            for (int j = 0; j < 4; j++) {
                a[i][j]     = (double)E[i * 4 + j];
                a[i][4 + j] = (i == j) ? 1.0 : 0.0;
            }
        for (int c = 0; c < 4; c++) {
            int piv = c; double best = fabs(a[c][c]);
            for (int r = c + 1; r < 4; r++) {
                double v = fabs(a[r][c]);
                if (v > best) { best = v; piv = r; }
            }
            if (piv != c)
                for (int j = 0; j < 8; j++) {
                    double tmp = a[c][j]; a[c][j] = a[piv][j]; a[piv][j] = tmp;
                }
            double inv = 1.0 / a[c][c];
            for (int j = 0; j < 8; j++) a[c][j] *= inv;
            for (int r = 0; r < 4; r++) {
                if (r == c) continue;
                double f = a[r][c];
                for (int j = 0; j < 8; j++) a[r][j] -= f * a[c][j];
            }
        }
        const float* K = intr + t * 9;
        double rs[3] = {(double)WW, (double)HH, 1.0};
        for (int i = 0; i < 3; i++)
            for (int k = 0; k < 4; k++) {
                double s = 0.0;
                for (int j = 0; j < 3; j++) s += (double)K[i * 3 + j] * rs[i] * a[j][4 + k];
                Pd[t * 12 + i * 4 + k] = s;
            }
        for (int k = 0; k < 4; k++) e2d[t * 4 + k] = a[2][4 + k];
    }
}

// K2: bulk copy disps -> fused output (memory-bound, float4)
__global__ __launch_bounds__(256) void copy_kernel(const float4* __restrict__ src,
                                                   float4* __restrict__ dst) {
    int i = blockIdx.x * blockDim.x + threadIdx.x;
    dst[i] = src[i];
}

// K2b: clear winner cells for every touched pixel (robust to ws poison value)
__global__ __launch_bounds__(256) void clear_kernel(const float* __restrict__ mk0,
                             const float* __restrict__ mk1,
                             const int* __restrict__ mbids, char* __restrict__ ws) {
    int id = blockIdx.x * blockDim.x + threadIdx.x;
    if (id >= 2 * NPTS) return;
    int n = id >> 1, v = id & 1;
    const float* mk = v ? mk1 : mk0;
    int xi = clampi((int)mk[2 * n], 0, WW - 1);
    int yi = clampi((int)mk[2 * n + 1], 0, HH - 1);
    int bid = mbids[n];
    int* winner = (int*)(ws + OFF_WIN);
    winner[(v * BB + bid) * IMG + yi * WW + xi] = -1;
}

// K3: per-point 4x4 AtA Jacobi eigensolve, z/valid, wave-reduced near-far atomics, scatter vote
template <bool DIRECT>
__global__ __launch_bounds__(256, 2) void solve_kernel(const float* __restrict__ mk0,
                             const float* __restrict__ mk1,
                             const int* __restrict__ mbids, const float* __restrict__ disps,
                             float* __restrict__ out, char* __restrict__ ws) {
    int n = blockIdx.x * blockDim.x + threadIdx.x;
    if (n >= NPTS) return;
    const double* Pd  = (const double*)(ws + OFF_PD);
    const double* e2d = (const double*)(ws + OFF_E2);
    int*   hasb   = (int*)(ws + OFF_HAS);
    float* valarr = (float*)(ws + OFF_VAL);
    int*   pixarr = (int*)(ws + OFF_PIX);
    int*   winner = (int*)(ws + OFF_WIN);
    float* near_  = out + FUSED;
    float* far_   = out + FUSED + BB * VV;

    int bid = mbids[n];
    float xf[2] = {mk0[2 * n], mk1[2 * n]};
    float yf[2] = {mk0[2 * n + 1], mk1[2 * n + 1]};

    // M = A^T A  (mconf is a uniform positive scale of A -> no effect on eigvecs)
    double M[4][4];
#pragma unroll
    for (int i = 0; i < 4; i++)
#pragma unroll
        for (int j = 0; j < 4; j++) M[i][j] = 0.0;
#pragma unroll
    for (int v = 0; v < 2; v++) {
        const double* P = Pd + (bid * VV + v) * 12;
        double xx = (double)xf[v], yy = (double)yf[v];
        double r0[4], r1[4];
#pragma unroll
        for (int j = 0; j < 4; j++) {
            r0[j] = xx * P[8 + j] - P[j];
            r1[j] = yy * P[8 + j] - P[4 + j];
        }
#pragma unroll
        for (int i = 0; i < 4; i++)
#pragma unroll
            for (int j = 0; j < 4; j++) M[i][j] += r0[i] * r0[j] + r1[i] * r1[j];
    }

    // cyclic Jacobi, f64, eigvec accumulation in Vm (all static indexing)
    double Vm[4][4] = {{1, 0, 0, 0}, {0, 1, 0, 0}, {0, 0, 1, 0}, {0, 0, 0, 1}};
    for (int sweep = 0; sweep < 8; ++sweep) {
        double off = fabs(M[0][1]) + fabs(M[0][2]) + fabs(M[0][3]) +
                     fabs(M[1][2]) + fabs(M[1][3]) + fabs(M[2][3]);
        double dia = fabs(M[0][0]) + fabs(M[1][1]) + fabs(M[2][2]) + fabs(M[3][3]);
        if (off <= 1e-13 * dia) break;
#pragma unroll
        for (int p = 0; p < 3; p++) {
#pragma unroll
            for (int q = p + 1; q < 4; q++) {
                double apq = M[p][q];
                if (fabs(apq) < 1e-300) continue;
                double tau = (M[q][q] - M[p][p]) / (2.0 * apq);
                double rt  = sqrt(1.0 + tau * tau);
                double t_  = (tau >= 0.0) ? 1.0 / (tau + rt) : 1.0 / (tau - rt);
                double c = 1.0 / sqrt(1.0 + t_ * t_);
                double s = t_ * c;
#pragma unroll
                for (int k = 0; k < 4; k++) {        // M := M*J (columns)
                    double mp = M[k][p], mq = M[k][q];
                    M[k][p] = c * mp - s * mq;
                    M[k][q] = s * mp + c * mq;
                }
#pragma unroll
                for (int k = 0; k < 4; k++) {        // M := J^T*M (rows)
                    double mp = M[p][k], mq = M[q][k];
                    M[p][k] = c * mp - s * mq;
                    M[q][k] = s * mp + c * mq;
                }
#pragma unroll
                for (int k = 0; k < 4; k++) {        // Vm := Vm*J
                    double vp = Vm[k][p], vq = Vm[k][q];
                    Vm[k][p] = c * vp - s * vq;
                    Vm[k][q] = s * vp + c * vq;
                }
            }
        }
    }
    int jmin = 0; double dmin = M[0][0];
    if (M[1][1] < dmin) { dmin = M[1][1]; jmin = 1; }
    if (M[2][2] < dmin) { dmin = M[2][2]; jmin = 2; }
    if (M[3][3] < dmin) { dmin = M[3][3]; jmin = 3; }

    // extract eigvec column jmin without dynamic array indexing (select chains)
    double ev[4];
#pragma unroll
    for (int i = 0; i < 4; i++) {
        double a01 = (jmin == 0) ? Vm[i][0] : Vm[i][1];
        double a23 = (jmin == 2) ? Vm[i][2] : Vm[i][3];
        ev[i] = (jmin < 2) ? a01 : a23;
    }

    double iw = 1.0 / ev[3];
    double pwx = ev[0] * iw, pwy = ev[1] * iw, pwz = ev[2] * iw;

    double z[2];
#pragma unroll
    for (int v = 0; v < 2; v++) {
        const double* e = e2d + (bid * VV + v) * 4;
        z[v] = e[0] * pwx + e[1] * pwy + e[2] * pwz + e[3];
    }
    bool valid = (z[0] > 0.0) && (z[0] < 500.0) && (z[1] > 0.0) && (z[1] < 500.0);

    // ---- near/far/has: wave-level segmented reduction, then one atomic per wave.
    // mbids sorted -> almost every wave has uniform bid; boundary waves fall back.
    unsigned long long vb = __ballot(valid);
    int bidFirst = __shfl(bid, 0);
    int bidLast  = __shfl(bid, 63);
    if (bidFirst == bidLast) {
        if (vb != 0ULL) {
            float zn[2], zf[2];
#pragma unroll
            for (int v = 0; v < 2; v++) {
                zn[v] = valid ? (float)z[v] : INFINITY;
                zf[v] = valid ? (float)z[v] : -1.0f;
            }
#pragma unroll
            for (int off = 32; off > 0; off >>= 1) {
#pragma unroll
                for (int v = 0; v < 2; v++) {
                    zn[v] = fminf(zn[v], __shfl_down(zn[v], off));
                    zf[v] = fmaxf(zf[v], __shfl_down(zf[v], off));
                }
            }
            if ((threadIdx.x & 63) == 0) {
#pragma unroll
                for (int v = 0; v < 2; v++) {
                    atomicMin((int*)(near_ + bid * VV + v), __float_as_int(zn[v]));
                    atomicMax((int*)(far_  + bid * VV + v), __float_as_int(zf[v]));
                }
                atomicOr(hasb + bid, 1);
            }
        }
    } else if (valid) {   // rare boundary wave
#pragma unroll
        for (int v = 0; v < 2; v++) {
            int fb = __float_as_int((float)z[v]);
            atomicMin((int*)(near_ + bid * VV + v), fb);
            atomicMax((int*)(far_  + bid * VV + v), fb);
        }
        atomicOr(hasb + bid, 1);
    }

#pragma unroll
    for (int v = 0; v < 2; v++) {
        int xi = clampi((int)xf[v], 0, WW - 1);
        int yi = clampi((int)yf[v], 0, HH - 1);
        int pix = (v * BB + bid) * IMG + yi * WW + xi;
        float cost = disps[pix];
        float val = valid ? (float)(0.5 * (1.0 / z[v]) + 0.5 * (double)cost) : cost;
        if (DIRECT) {
            out[pix] = val;   // fallback: nondeterministic duplicate order
        } else {
            valarr[2 * n + v] = val;
            pixarr[2 * n + v] = pix;
            atomicMax(winner + pix, n);   // last-update-wins == max n (distinct addrs, uncontended)
        }
    }
}

// K4: winner writes its val (deterministic duplicate resolution)
__global__ __launch_bounds__(256) void resolve_kernel(float* __restrict__ out,
                                                      const char* __restrict__ ws) {
    int id = blockIdx.x * blockDim.x + threadIdx.x;
    if (id >= 2 * NPTS) return;
    const float* valarr = (const float*)(ws + OFF_VAL);
    const int*   pixarr = (const int*)(ws + OFF_PIX);
    const int*   winner = (const int*)(ws + OFF_WIN);
    int pix = pixarr[id];
    if (winner[pix] == (id >> 1)) out[pix] = valarr[id];
}

// K5: apply flag gating to near/far, write flag
__global__ __launch_bounds__(64) void finalize_kernel(float* __restrict__ out,
                                                      const char* __restrict__ ws) {
    int t = threadIdx.x;
    if (t >= BB * VV) return;
    const int* hasb = (const int*)(ws + OFF_HAS);
    int has = hasb[t / VV];
    float* near_ = out + FUSED;
    float* far_  = out + FUSED + BB * VV;
    float* flag_ = out + FUSED + 2 * BB * VV;
    near_[t] = has ? near_[t] : 0.0f;
    far_[t]  = has ? far_[t]  : 500.0f;
    flag_[t] = has ? 1.0f : 0.0f;
}

extern "C" void kernel_launch(void* const* d_in, const int* in_sizes, int n_in,
                              void* d_out, int out_size, void* d_ws, size_t ws_size,
                              hipStream_t stream) {
    const float* mk0   = (const float*)d_in[0];
    const float* mk1   = (const float*)d_in[1];
    // d_in[2] = mconf: uniform positive scale of A, no effect on null vector -> unused
    const int*   mbids = (const int*)d_in[3];
    const float* intr  = (const float*)d_in[4];
    const float* extr  = (const float*)d_in[5];
    const float* disps = (const float*)d_in[6];
    float* out = (float*)d_out;
    char*  ws  = (char*)d_ws;

    bool dedup = (ws_size >= WS_NEED);

    prep_kernel<<<1, 64, 0, stream>>>(intr, extr, out, ws);
    copy_kernel<<<FUSED / 4 / 256, 256, 0, stream>>>((const float4*)disps, (float4*)out);
    if (dedup) {
        clear_kernel<<<(2 * NPTS + 255) / 256, 256, 0, stream>>>(mk0, mk1, mbids, ws);
        solve_kernel<false><<<(NPTS + 255) / 256, 256, 0, stream>>>(mk0, mk1, mbids, disps, out, ws);
        resolve_kernel<<<(2 * NPTS + 255) / 256, 256, 0, stream>>>(out, ws);
    } else {
        solve_kernel<true><<<(NPTS + 255) / 256, 256, 0, stream>>>(mk0, mk1, mbids, disps, out, ws);
    }
    finalize_kernel<<<1, 64, 0, stream>>>(out, ws);
}

// Round 5
// 214.864 us; speedup vs baseline: 7.8805x; 1.0513x over previous
//
#include <hip/hip_runtime.h>
#include <math.h>

#define BB 8
#define VV 2
#define HH 1024
#define WW 1024
#define NPTS 131072
#define IMG (HH*WW)
#define FUSED (VV*BB*IMG)   // 16777216

// ---- workspace layout (bytes)
#define OFF_PD   0u                         // double[16*12] P  (contiguous with E2)
#define OFF_E2   1536u                      // double[16*4]  e2
#define OFF_HAS  2048u                      // int[8]
#define OFF_Z    2304u                      // float[2*NPTS]   (z, 0 = invalid)
#define OFF_PIX  (2304u + 8u*NPTS)          // int[2*NPTS]
#define OFF_WIN  (OFF_PIX + 8u*NPTS)        // int[FUSED] = 64 MiB
#define WS_NEED  ((size_t)OFF_WIN + 4ull*(size_t)FUSED)

#define NCOPY  (FUSED/4/256)   // 16384 copy blocks (float4)
#define NCLEAR ((2*NPTS)/256)  // 1024 clear blocks

__device__ __forceinline__ int clampi(int v, int lo, int hi) {
    return v < lo ? lo : (v > hi ? hi : v);
}

// K1: fused  (a) bulk copy disps->out  (b) clear winner cells for touched pixels
//            (c) init near/far/has     (d) per-(b,v) P = intr*rowscale @ inv(E)[:3,:], e2 = inv(E)[2,:]
__global__ __launch_bounds__(256) void setup_kernel(
        const float4* __restrict__ src, float4* __restrict__ dst,
        const float* __restrict__ mk0, const float* __restrict__ mk1,
        const int* __restrict__ mbids,
        const float* __restrict__ intr, const float* __restrict__ extr,
        float* __restrict__ out, char* __restrict__ ws, int dedup) {
    int b = blockIdx.x, t = threadIdx.x;
    if (b < NCOPY) {                       // (a) copy
        int i = b * 256 + t;
        dst[i] = src[i];
        return;
    }
    int cb = b - NCOPY;
    int id = cb * 256 + t;                 // (b) clear winner for touched pixel
    if (dedup) {
        int n = id >> 1, v = id & 1;
        const float* mk = v ? mk1 : mk0;
        int xi = clampi((int)mk[2 * n], 0, WW - 1);
        int yi = clampi((int)mk[2 * n + 1], 0, HH - 1);
        int bid = mbids[n];
        ((int*)(ws + OFF_WIN))[(v * BB + bid) * IMG + yi * WW + xi] = -1;
    }
    if (cb == 0) {                         // (c)+(d) in one block
        if (t < BB) ((int*)(ws + OFF_HAS))[t] = 0;
        if (t < BB * VV) {
            float* near_ = out + FUSED;
            float* far_  = out + FUSED + BB * VV;
            near_[t] = INFINITY;   // positive -> signed-int atomicMin ok
            far_[t]  = 0.0f;       // any positive z beats it under signed atomicMax
            double* Pd  = (double*)(ws + OFF_PD);
            double* e2d = (double*)(ws + OFF_E2);
            const float* E = extr + t * 16;
            double a[4][8];
            for (int i = 0; i < 4; i++)
                for (int j = 0; j < 4; j++) {
                    a[i][j]     = (double)E[i * 4 + j];
                    a[i][4 + j] = (i == j) ? 1.0 : 0.0;
                }
            for (int c = 0; c < 4; c++) {
                int piv = c; double best = fabs(a[c][c]);
                for (int r = c + 1; r < 4; r++) {
                    double v = fabs(a[r][c]);
                    if (v > best) { best = v; piv = r; }
                }
                if (piv != c)
                    for (int j = 0; j < 8; j++) {
                        double tmp = a[c][j]; a[c][j] = a[piv][j]; a[piv][j] = tmp;
                    }
                double inv = 1.0 / a[c][c];
                for (int j = 0; j < 8; j++) a[c][j] *= inv;
                for (int r = 0; r < 4; r++) {
                    if (r == c) continue;
                    double f = a[r][c];
                    for (int j = 0; j < 8; j++) a[r][j] -= f * a[c][j];
                }
            }
            const float* K = intr + t * 9;
            double rs[3] = {(double)WW, (double)HH, 1.0};
            for (int i = 0; i < 3; i++)
                for (int k = 0; k < 4; k++) {
                    double s = 0.0;
                    for (int j = 0; j < 3; j++) s += (double)K[i * 3 + j] * rs[i] * a[j][4 + k];
                    Pd[t * 12 + i * 4 + k] = s;
                }
            for (int k = 0; k < 4; k++) e2d[t * 4 + k] = a[2][4 + k];
        }
    }
}

// K2: per-point 4x4 AtA Jacobi eigensolve (f64, verified), z/valid,
//     wave-reduced near/far atomics, scatter vote (no disps gather in dedup path)
template <bool DIRECT>
__global__ __launch_bounds__(256) void solve_kernel(
        const float2* __restrict__ mk0, const float2* __restrict__ mk1,
        const int* __restrict__ mbids, const float* __restrict__ disps,
        float* __restrict__ out, char* __restrict__ ws) {
    __shared__ double sD[256];             // 192 P doubles + 64 e2 doubles
    int t = threadIdx.x;
    sD[t] = ((const double*)(ws + OFF_PD))[t];
    __syncthreads();

    int n = blockIdx.x * 256 + t;          // grid is exactly NPTS/256
    int*   hasb   = (int*)(ws + OFF_HAS);
    float* zarr   = (float*)(ws + OFF_Z);
    int*   pixarr = (int*)(ws + OFF_PIX);
    int*   winner = (int*)(ws + OFF_WIN);
    float* near_  = out + FUSED;
    float* far_   = out + FUSED + BB * VV;

    int bid = mbids[n];
    float2 q0 = mk0[n], q1 = mk1[n];
    float xf[2] = {q0.x, q1.x};
    float yf[2] = {q0.y, q1.y};

    // M = A^T A  (mconf is a uniform positive scale of A -> no effect on eigvecs)
    double M[4][4];
#pragma unroll
    for (int i = 0; i < 4; i++)
#pragma unroll
        for (int j = 0; j < 4; j++) M[i][j] = 0.0;
#pragma unroll
    for (int v = 0; v < 2; v++) {
        const double* P = sD + (bid * VV + v) * 12;
        double xx = (double)xf[v], yy = (double)yf[v];
        double r0[4], r1[4];
#pragma unroll
        for (int j = 0; j < 4; j++) {
            r0[j] = xx * P[8 + j] - P[j];
            r1[j] = yy * P[8 + j] - P[4 + j];
        }
#pragma unroll
        for (int i = 0; i < 4; i++)
#pragma unroll
            for (int j = 0; j < 4; j++) M[i][j] += r0[i] * r0[j] + r1[i] * r1[j];
    }

    // cyclic Jacobi, f64, eigvec accumulation in Vm (verified in R3: absmax 32)
    double Vm[4][4] = {{1, 0, 0, 0}, {0, 1, 0, 0}, {0, 0, 1, 0}, {0, 0, 0, 1}};
    for (int sweep = 0; sweep < 8; ++sweep) {
        double off = fabs(M[0][1]) + fabs(M[0][2]) + fabs(M[0][3]) +
                     fabs(M[1][2]) + fabs(M[1][3]) + fabs(M[2][3]);
        double dia = fabs(M[0][0]) + fabs(M[1][1]) + fabs(M[2][2]) + fabs(M[3][3]);
        if (off <= 1e-13 * dia) break;
#pragma unroll
        for (int p = 0; p < 3; p++) {
#pragma unroll
            for (int q = p + 1; q < 4; q++) {
                double apq = M[p][q];
                if (fabs(apq) < 1e-300) continue;
                double tau = (M[q][q] - M[p][p]) / (2.0 * apq);
                double rt  = sqrt(1.0 + tau * tau);
                double t_  = (tau >= 0.0) ? 1.0 / (tau + rt) : 1.0 / (tau - rt);
                double c = 1.0 / sqrt(1.0 + t_ * t_);
                double s = t_ * c;
#pragma unroll
                for (int k = 0; k < 4; k++) {        // M := M*J (columns)
                    double mp = M[k][p], mq = M[k][q];
                    M[k][p] = c * mp - s * mq;
                    M[k][q] = s * mp + c * mq;
                }
#pragma unroll
                for (int k = 0; k < 4; k++) {        // M := J^T*M (rows)
                    double mp = M[p][k], mq = M[q][k];
                    M[p][k] = c * mp - s * mq;
                    M[q][k] = s * mp + c * mq;
                }
#pragma unroll
                for (int k = 0; k < 4; k++) {        // Vm := Vm*J
                    double vp = Vm[k][p], vq = Vm[k][q];
                    Vm[k][p] = c * vp - s * vq;
                    Vm[k][q] = s * vp + c * vq;
                }
            }
        }
    }
    int jmin = 0; double dmin = M[0][0];
    if (M[1][1] < dmin) { dmin = M[1][1]; jmin = 1; }
    if (M[2][2] < dmin) { dmin = M[2][2]; jmin = 2; }
    if (M[3][3] < dmin) { dmin = M[3][3]; jmin = 3; }

    // extract eigvec column jmin without dynamic indexing (select chains)
    double ev[4];
#pragma unroll
    for (int i = 0; i < 4; i++) {
        double a01 = (jmin == 0) ? Vm[i][0] : Vm[i][1];
        double a23 = (jmin == 2) ? Vm[i][2] : Vm[i][3];
        ev[i] = (jmin < 2) ? a01 : a23;
    }

    double iw  = 1.0 / ev[3];
    double pwx = ev[0] * iw, pwy = ev[1] * iw, pwz = ev[2] * iw;

    double z[2];
#pragma unroll
    for (int v = 0; v < 2; v++) {
        const double* e = sD + 192 + (bid * VV + v) * 4;
        z[v] = e[0] * pwx + e[1] * pwy + e[2] * pwz + e[3];
    }
    bool valid = (z[0] > 0.0) && (z[0] < 500.0) && (z[1] > 0.0) && (z[1] < 500.0);

    // near/far/has: wave-level segmented reduction (mbids sorted), one atomic per wave
    unsigned long long vb = __ballot(valid);
    int bidFirst = __shfl(bid, 0);
    int bidLast  = __shfl(bid, 63);
    if (bidFirst == bidLast) {
        if (vb != 0ULL) {
            float zn[2], zf[2];
#pragma unroll
            for (int v = 0; v < 2; v++) {
                zn[v] = valid ? (float)z[v] : INFINITY;
                zf[v] = valid ? (float)z[v] : -1.0f;
            }
#pragma unroll
            for (int off = 32; off > 0; off >>= 1) {
#pragma unroll
                for (int v = 0; v < 2; v++) {
                    zn[v] = fminf(zn[v], __shfl_down(zn[v], off));
                    zf[v] = fmaxf(zf[v], __shfl_down(zf[v], off));
                }
            }
            if ((threadIdx.x & 63) == 0) {
#pragma unroll
                for (int v = 0; v < 2; v++) {
                    atomicMin((int*)(near_ + bid * VV + v), __float_as_int(zn[v]));
                    atomicMax((int*)(far_  + bid * VV + v), __float_as_int(zf[v]));
                }
                atomicOr(hasb + bid, 1);
            }
        }
    } else if (valid) {        // rare boundary wave
#pragma unroll
        for (int v = 0; v < 2; v++) {
            int fb = __float_as_int((float)z[v]);
            atomicMin((int*)(near_ + bid * VV + v), fb);
            atomicMax((int*)(far_  + bid * VV + v), fb);
        }
        atomicOr(hasb + bid, 1);
    }

    // scatter vote (no disps gather in the dedup path)
#pragma unroll
    for (int v = 0; v < 2; v++) {
        int xi = clampi((int)xf[v], 0, WW - 1);
        int yi = clampi((int)yf[v], 0, HH - 1);
        int pix = (v * BB + bid) * IMG + yi * WW + xi;
        if (DIRECT) {
            float cost = disps[pix];
            float val = valid ? (float)(0.5 * (1.0 / z[v]) + 0.5 * (double)cost) : cost;
            out[pix] = val;    // fallback: nondeterministic duplicate order
        } else {
            zarr[2 * n + v]   = valid ? (float)z[v] : 0.0f;
            pixarr[2 * n + v] = pix;
            atomicMax(winner + pix, n);   // last-update-wins == max n
        }
    }
}

// K3: winner writes its val (invalid winner => pixel already holds cost); + finalize near/far/flag
__global__ __launch_bounds__(256) void resolve_kernel(const float* __restrict__ disps,
                                                      float* __restrict__ out,
                                                      const char* __restrict__ ws) {
    int id = blockIdx.x * 256 + threadIdx.x;   // grid exactly NCLEAR
    const float* zarr   = (const float*)(ws + OFF_Z);
    const int*   pixarr = (const int*)(ws + OFF_PIX);
    const int*   winner = (const int*)(ws + OFF_WIN);
    int   pix = pixarr[id];
    float zf  = zarr[id];
    if (winner[pix] == (id >> 1) && zf > 0.0f) {
        float cost = disps[pix];
        out[pix] = (float)(0.5 * (1.0 / (double)zf) + 0.5 * (double)cost);
    }
    if (blockIdx.x == 0 && threadIdx.x < BB * VV) {
        int tt = threadIdx.x;
        const int* hasb = (const int*)(ws + OFF_HAS);
        int has = hasb[tt / VV];
        float* near_ = out + FUSED;
        float* far_  = out + FUSED + BB * VV;
        float* flag_ = out + FUSED + 2 * BB * VV;
        near_[tt] = has ? near_[tt] : 0.0f;
        far_[tt]  = has ? far_[tt]  : 500.0f;
        flag_[tt] = has ? 1.0f : 0.0f;
    }
}

// fallback-path finalize (dedup==false only)
__global__ __launch_bounds__(64) void finalize_kernel(float* __restrict__ out,
                                                      const char* __restrict__ ws) {
    int t = threadIdx.x;
    if (t >= BB * VV) return;
    const int* hasb = (const int*)(ws + OFF_HAS);
    int has = hasb[t / VV];
    float* near_ = out + FUSED;
    float* far_  = out + FUSED + BB * VV;
    float* flag_ = out + FUSED + 2 * BB * VV;
    near_[t] = has ? near_[t] : 0.0f;
    far_[t]  = has ? far_[t]  : 500.0f;
    flag_[t] = has ? 1.0f : 0.0f;
}

extern "C" void kernel_launch(void* const* d_in, const int* in_sizes, int n_in,
                              void* d_out, int out_size, void* d_ws, size_t ws_size,
                              hipStream_t stream) {
    const float* mk0   = (const float*)d_in[0];
    const float* mk1   = (const float*)d_in[1];
    // d_in[2] = mconf: uniform positive scale of A, no effect on null vector -> unused
    const int*   mbids = (const int*)d_in[3];
    const float* intr  = (const float*)d_in[4];
    const float* extr  = (const float*)d_in[5];
    const float* disps = (const float*)d_in[6];
    float* out = (float*)d_out;
    char*  ws  = (char*)d_ws;

    bool dedup = (ws_size >= WS_NEED);

    setup_kernel<<<NCOPY + NCLEAR, 256, 0, stream>>>(
        (const float4*)disps, (float4*)out, mk0, mk1, mbids, intr, extr, out, ws,
        dedup ? 1 : 0);
    if (dedup) {
        solve_kernel<false><<<NPTS / 256, 256, 0, stream>>>(
            (const float2*)mk0, (const float2*)mk1, mbids, disps, out, ws);
        resolve_kernel<<<NCLEAR, 256, 0, stream>>>(disps, out, ws);
    } else {
        solve_kernel<true><<<NPTS / 256, 256, 0, stream>>>(
            (const float2*)mk0, (const float2*)mk1, mbids, disps, out, ws);
        finalize_kernel<<<1, 64, 0, stream>>>(out, ws);
    }
}

// Round 6
// 206.708 us; speedup vs baseline: 8.1914x; 1.0395x over previous
//
#include <hip/hip_runtime.h>
#include <math.h>

#define BB 8
#define VV 2
#define HH 1024
#define WW 1024
#define NPTS 131072
#define IMG (HH*WW)
#define FUSED (VV*BB*IMG)   // 16777216

#define NSOLVE (NPTS/256)      // 512 solve blocks
#define NCLEAR ((2*NPTS)/256)  // 1024 clear blocks
#define NCOPY  (FUSED/4/256)   // 16384 copy blocks (float4)

// ---- workspace layout (bytes)
#define OFF_Z    0u                          // float[2*NPTS] (z, 0 = invalid)
#define OFF_PIX  (8u*NPTS)                   // int[2*NPTS]
#define OFF_RED  (16u*NPTS)                  // int[NSOLVE*40] block slots: 16 near,16 far,8 has
#define OFF_WIN  (OFF_RED + 0x20000u)        // int[FUSED] = 64 MiB
#define WS_NEED  ((size_t)OFF_WIN + 4ull*(size_t)FUSED)

__device__ __forceinline__ int clampi(int v, int lo, int hi) {
    return v < lo ? lo : (v > hi ? hi : v);
}

// per-(b,v) prep (t = 0..15): P = (intr*rowscale) @ inv(E)[:3,:] -> sD[t*12..],
// e2 = inv(E)[2,:] -> sD[192 + t*4..].  f64 Gauss-Jordan w/ partial pivoting.
__device__ void prep_one(int t, const float* __restrict__ intr,
                         const float* __restrict__ extr, double* sD) {
    const float* E = extr + t * 16;
    double a[4][8];
    for (int i = 0; i < 4; i++)
        for (int j = 0; j < 4; j++) {
            a[i][j]     = (double)E[i * 4 + j];
            a[i][4 + j] = (i == j) ? 1.0 : 0.0;
        }
    for (int c = 0; c < 4; c++) {
        int piv = c; double best = fabs(a[c][c]);
        for (int r = c + 1; r < 4; r++) {
            double v = fabs(a[r][c]);
            if (v > best) { best = v; piv = r; }
        }
        if (piv != c)
            for (int j = 0; j < 8; j++) {
                double tmp = a[c][j]; a[c][j] = a[piv][j]; a[piv][j] = tmp;
            }
        double inv = 1.0 / a[c][c];
        for (int j = 0; j < 8; j++) a[c][j] *= inv;
        for (int r = 0; r < 4; r++) {
            if (r == c) continue;
            double f = a[r][c];
            for (int j = 0; j < 8; j++) a[r][j] -= f * a[c][j];
        }
    }
    const float* K = intr + t * 9;
    double rs[3] = {(double)WW, (double)HH, 1.0};
    for (int i = 0; i < 3; i++)
        for (int k = 0; k < 4; k++) {
            double s = 0.0;
            for (int j = 0; j < 3; j++) s += (double)K[i * 3 + j] * rs[i] * a[j][4 + k];
            sD[t * 12 + i * 4 + k] = s;
        }
    for (int k = 0; k < 4; k++) sD[192 + t * 4 + k] = a[2][4 + k];
}

// K1: fused. blocks [0,NSOLVE): per-point Jacobi solve (stores z,pix + block near/far slot);
//            [NSOLVE, NSOLVE+NCLEAR): clear winner cells; rest: bulk copy disps->out.
// Solve blocks placed FIRST so copy waves fill their latency bubbles.
template <int DEDUP>
__global__ __launch_bounds__(256) void mega_kernel(
        const float4* __restrict__ src, float4* __restrict__ dst,
        const float2* __restrict__ mk0, const float2* __restrict__ mk1,
        const int* __restrict__ mbids,
        const float* __restrict__ intr, const float* __restrict__ extr,
        const float* __restrict__ disps,
        float* __restrict__ out, char* __restrict__ ws) {
    int b = blockIdx.x, t = threadIdx.x;

    if (b >= NSOLVE + NCLEAR) {            // ---- copy role
        int i = (b - NSOLVE - NCLEAR) * 256 + t;
        dst[i] = src[i];
        return;
    }
    if (b >= NSOLVE) {                     // ---- clear-winner role
        if (DEDUP) {
            int id = (b - NSOLVE) * 256 + t;
            int n = id >> 1, v = id & 1;
            const float2* mk = v ? mk1 : mk0;
            float2 q = mk[n];
            int xi = clampi((int)q.x, 0, WW - 1);
            int yi = clampi((int)q.y, 0, HH - 1);
            int bid = mbids[n];
            ((int*)(ws + OFF_WIN))[(v * BB + bid) * IMG + yi * WW + xi] = -1;
        }
        return;
    }

    // ---- solve role
    __shared__ double sD[256];             // 192 P doubles + 64 e2 doubles
    __shared__ int nearB[16], farB[16], hasB[8];
    if (t < 16) {
        prep_one(t, intr, extr, sD);
        nearB[t] = 0x7F800000;             // +inf bits
        farB[t]  = 0;                      // 0.0f bits
        if (t < 8) hasB[t] = 0;
    }
    __syncthreads();

    int n = b * 256 + t;
    float* zarr   = (float*)(ws + OFF_Z);
    int*   pixarr = (int*)(ws + OFF_PIX);
    int*   winner = (int*)(ws + OFF_WIN);

    int bid = mbids[n];
    float2 q0 = mk0[n], q1 = mk1[n];
    float xf[2] = {q0.x, q1.x};
    float yf[2] = {q0.y, q1.y};

    // M = A^T A  (mconf is a uniform positive scale of A -> no effect on eigvecs)
    double M[4][4];
#pragma unroll
    for (int i = 0; i < 4; i++)
#pragma unroll
        for (int j = 0; j < 4; j++) M[i][j] = 0.0;
#pragma unroll
    for (int v = 0; v < 2; v++) {
        const double* P = sD + (bid * VV + v) * 12;
        double xx = (double)xf[v], yy = (double)yf[v];
        double r0[4], r1[4];
#pragma unroll
        for (int j = 0; j < 4; j++) {
            r0[j] = xx * P[8 + j] - P[j];
            r1[j] = yy * P[8 + j] - P[4 + j];
        }
#pragma unroll
        for (int i = 0; i < 4; i++)
#pragma unroll
            for (int j = 0; j < 4; j++) M[i][j] += r0[i] * r0[j] + r1[i] * r1[j];
    }

    // cyclic Jacobi, f64 (verified: absmax 32)
    double Vm[4][4] = {{1, 0, 0, 0}, {0, 1, 0, 0}, {0, 0, 1, 0}, {0, 0, 0, 1}};
    for (int sweep = 0; sweep < 8; ++sweep) {
        double off = fabs(M[0][1]) + fabs(M[0][2]) + fabs(M[0][3]) +
                     fabs(M[1][2]) + fabs(M[1][3]) + fabs(M[2][3]);
        double dia = fabs(M[0][0]) + fabs(M[1][1]) + fabs(M[2][2]) + fabs(M[3][3]);
        if (off <= 1e-13 * dia) break;
#pragma unroll
        for (int p = 0; p < 3; p++) {
#pragma unroll
            for (int q = p + 1; q < 4; q++) {
                double apq = M[p][q];
                if (fabs(apq) < 1e-300) continue;
                double tau = (M[q][q] - M[p][p]) / (2.0 * apq);
                double rt  = sqrt(1.0 + tau * tau);
                double t_  = (tau >= 0.0) ? 1.0 / (tau + rt) : 1.0 / (tau - rt);
                double c = 1.0 / sqrt(1.0 + t_ * t_);
                double s = t_ * c;
#pragma unroll
                for (int k = 0; k < 4; k++) {
                    double mp = M[k][p], mq = M[k][q];
                    M[k][p] = c * mp - s * mq;
                    M[k][q] = s * mp + c * mq;
                }
#pragma unroll
                for (int k = 0; k < 4; k++) {
                    double mp = M[p][k], mq = M[q][k];
                    M[p][k] = c * mp - s * mq;
                    M[q][k] = s * mp + c * mq;
                }
#pragma unroll
                for (int k = 0; k < 4; k++) {
                    double vp = Vm[k][p], vq = Vm[k][q];
                    Vm[k][p] = c * vp - s * vq;
                    Vm[k][q] = s * vp + c * vq;
                }
            }
        }
    }
    int jmin = 0; double dmin = M[0][0];
    if (M[1][1] < dmin) { dmin = M[1][1]; jmin = 1; }
    if (M[2][2] < dmin) { dmin = M[2][2]; jmin = 2; }
    if (M[3][3] < dmin) { dmin = M[3][3]; jmin = 3; }

    double ev[4];
#pragma unroll
    for (int i = 0; i < 4; i++) {
        double a01 = (jmin == 0) ? Vm[i][0] : Vm[i][1];
        double a23 = (jmin == 2) ? Vm[i][2] : Vm[i][3];
        ev[i] = (jmin < 2) ? a01 : a23;
    }
    double iw  = 1.0 / ev[3];
    double pwx = ev[0] * iw, pwy = ev[1] * iw, pwz = ev[2] * iw;

    double z[2];
#pragma unroll
    for (int v = 0; v < 2; v++) {
        const double* e = sD + 192 + (bid * VV + v) * 4;
        z[v] = e[0] * pwx + e[1] * pwy + e[2] * pwz + e[3];
    }
    bool valid = (z[0] > 0.0) && (z[0] < 500.0) && (z[1] > 0.0) && (z[1] < 500.0);

    // block-local near/far/has via LDS (no global atomics, no init ordering)
    unsigned long long vb = __ballot(valid);
    int bidFirst = __shfl(bid, 0);
    int bidLast  = __shfl(bid, 63);
    if (bidFirst == bidLast) {
        if (vb != 0ULL) {
            float zn[2], zf[2];
#pragma unroll
            for (int v = 0; v < 2; v++) {
                zn[v] = valid ? (float)z[v] : INFINITY;
                zf[v] = valid ? (float)z[v] : -1.0f;
            }
#pragma unroll
            for (int off = 32; off > 0; off >>= 1) {
#pragma unroll
                for (int v = 0; v < 2; v++) {
                    zn[v] = fminf(zn[v], __shfl_down(zn[v], off));
                    zf[v] = fmaxf(zf[v], __shfl_down(zf[v], off));
                }
            }
            if ((t & 63) == 0) {
#pragma unroll
                for (int v = 0; v < 2; v++) {
                    atomicMin(&nearB[bid * VV + v], __float_as_int(zn[v]));
                    atomicMax(&farB[bid * VV + v],  __float_as_int(zf[v]));
                }
                atomicOr(&hasB[bid], 1);
            }
        }
    } else if (valid) {        // rare boundary wave
#pragma unroll
        for (int v = 0; v < 2; v++) {
            int fb = __float_as_int((float)z[v]);
            atomicMin(&nearB[bid * VV + v], fb);
            atomicMax(&farB[bid * VV + v],  fb);
        }
        atomicOr(&hasB[bid], 1);
    }

#pragma unroll
    for (int v = 0; v < 2; v++) {
        int xi = clampi((int)xf[v], 0, WW - 1);
        int yi = clampi((int)yf[v], 0, HH - 1);
        int pix = (v * BB + bid) * IMG + yi * WW + xi;
        if (DEDUP) {
            zarr[2 * n + v]   = valid ? (float)z[v] : 0.0f;
            pixarr[2 * n + v] = pix;
        } else {
            float cost = disps[pix];
            float val = valid ? (float)(0.5 * (1.0 / z[v]) + 0.5 * (double)cost) : cost;
            out[pix] = val;    // fallback: nondeterministic duplicate order
        }
    }

    __syncthreads();
    int* red = (int*)(ws + OFF_RED) + b * 40;
    if (t < 16) {
        red[t]      = nearB[t];
        red[16 + t] = farB[t];
        if (t < 8) red[32 + t] = hasB[t];
    }
}

// K2: vote (runs after clear is complete; kernel boundary provides the ordering)
__global__ __launch_bounds__(256) void vote_kernel(char* __restrict__ ws) {
    int id = blockIdx.x * 256 + threadIdx.x;   // grid exactly NCLEAR
    const int* pixarr = (const int*)(ws + OFF_PIX);
    int* winner = (int*)(ws + OFF_WIN);
    atomicMax(winner + pixarr[id], id >> 1);   // last-update-wins == max n
}

// K3: winner writes its val; block 0 also reduces the per-block near/far/has slots.
__global__ __launch_bounds__(256) void resolve_kernel(const float* __restrict__ disps,
                                                      float* __restrict__ out,
                                                      const char* __restrict__ ws,
                                                      int dedup) {
    int id = blockIdx.x * 256 + threadIdx.x;
    if (dedup) {
        const float* zarr   = (const float*)(ws + OFF_Z);
        const int*   pixarr = (const int*)(ws + OFF_PIX);
        const int*   winner = (const int*)(ws + OFF_WIN);
        int   pix = pixarr[id];
        float zf  = zarr[id];
        if (winner[pix] == (id >> 1) && zf > 0.0f) {
            float cost = disps[pix];
            out[pix] = (float)(0.5 * (1.0 / (double)zf) + 0.5 * (double)cost);
        }
    }
    if (blockIdx.x == 0) {
        int t = threadIdx.x;
        const int* red = (const int*)(ws + OFF_RED);
        if (t < 16) {
            int nm = 0x7F800000, hv = 0;
            for (int s = 0; s < NSOLVE; s++) {
                const int* r = red + s * 40;
                nm = min(nm, r[t]);
                hv |= r[32 + (t >> 1)];
            }
            float* near_ = out + FUSED;
            float* flag_ = out + FUSED + 2 * BB * VV;
            near_[t] = hv ? __int_as_float(nm) : 0.0f;
            flag_[t] = hv ? 1.0f : 0.0f;
        } else if (t < 32) {
            int c = t - 16;
            int fm = 0, hv = 0;
            for (int s = 0; s < NSOLVE; s++) {
                const int* r = red + s * 40;
                fm = max(fm, r[16 + c]);
                hv |= r[32 + (c >> 1)];
            }
            float* far_ = out + FUSED + BB * VV;
            far_[c] = hv ? __int_as_float(fm) : 500.0f;
        }
    }
}

extern "C" void kernel_launch(void* const* d_in, const int* in_sizes, int n_in,
                              void* d_out, int out_size, void* d_ws, size_t ws_size,
                              hipStream_t stream) {
    const float* mk0   = (const float*)d_in[0];
    const float* mk1   = (const float*)d_in[1];
    // d_in[2] = mconf: uniform positive scale of A, no effect on null vector -> unused
    const int*   mbids = (const int*)d_in[3];
    const float* intr  = (const float*)d_in[4];
    const float* extr  = (const float*)d_in[5];
    const float* disps = (const float*)d_in[6];
    float* out = (float*)d_out;
    char*  ws  = (char*)d_ws;

    bool dedup = (ws_size >= WS_NEED);
    dim3 grid(NSOLVE + NCLEAR + NCOPY);

    if (dedup) {
        mega_kernel<1><<<grid, 256, 0, stream>>>(
            (const float4*)disps, (float4*)out, (const float2*)mk0, (const float2*)mk1,
            mbids, intr, extr, disps, out, ws);
        vote_kernel<<<NCLEAR, 256, 0, stream>>>(ws);
        resolve_kernel<<<NCLEAR, 256, 0, stream>>>(disps, out, ws, 1);
    } else {
        mega_kernel<0><<<grid, 256, 0, stream>>>(
            (const float4*)disps, (float4*)out, (const float2*)mk0, (const float2*)mk1,
            mbids, intr, extr, disps, out, ws);
        resolve_kernel<<<1, 256, 0, stream>>>(disps, out, ws, 0);
    }
}